// Round 9
// baseline (105.651 us; speedup 1.0000x reference)
//
#include <hip/hip_runtime.h>
#include <hip/hip_fp16.h>

#define HW 128
#define PLANE (HW * HW)

typedef __attribute__((ext_vector_type(8))) _Float16 f16x8;
typedef __attribute__((ext_vector_type(4))) float f32x4;

__device__ __forceinline__ unsigned short f2h(float f) {
  return __half_as_ushort(__float2half(f));
}

// XCD-aware bijective swizzle (nwg % 8 == 0): XCD k gets a contiguous chunk.
__device__ __forceinline__ void tile_from_bid_512(int bid, int& b, int& by, int& bx) {
  int wg = (bid & 7) * 64 + (bid >> 3);
  b = wg >> 6;
  int t = wg & 63;
  by = (t >> 3) << 4;
  bx = (t & 7) << 4;
}

// ---------------- fused weight packing (all three) ----------------
__global__ __launch_bounds__(256) void pack_all_kernel(
    const float* __restrict__ w1, const float* __restrict__ w2,
    const float* __restrict__ wd, unsigned short* __restrict__ w1p,
    unsigned short* __restrict__ w2p, unsigned short* __restrict__ wdp) {
  int idx = blockIdx.x * 256 + threadIdx.x;
  if (idx < 73728) {
    int k = idx >> 6, n = idx & 63;
    int tap = k >> 7, ic = k & 127;
    w1p[((k >> 3) * 64 + n) * 8 + (k & 7)] = f2h(w1[(n * 128 + ic) * 9 + tap]);
  } else if (idx < 73728 + 18432) {
    int i = idx - 73728;
    int k = i >> 5, n = i & 31;
    int tap = k >> 6, ic = k & 63;
    float v = (n < 18) ? w2[(n * 64 + ic) * 9 + tap] : 0.f;
    w2p[((k >> 3) * 32 + n) * 8 + (k & 7)] = f2h(v);
  } else if (idx < 73728 + 18432 + 36864) {
    int i = idx - 73728 - 18432;
    int k = i >> 6, n = i & 63;
    int tap = k >> 6, ic = k & 63;
    wdp[((k >> 3) * 64 + n) * 8 + (k & 7)] = f2h(wd[(n * 64 + ic) * 9 + tap]);
  }
}

// ---------------- ref,tgt NCHW fp32 -> NHWC fp16 ----------------
__global__ __launch_bounds__(256) void to_nhwc_kernel(
    const float* __restrict__ ref, const float* __restrict__ tgt,
    unsigned short* __restrict__ xref, unsigned short* __restrict__ xtgt) {
  __shared__ unsigned short lds[32][136];
  const int b = blockIdx.z, y = blockIdx.y, x0 = blockIdx.x * 32;
  for (int idx = threadIdx.x; idx < 4096; idx += 256) {
    int ic = idx >> 5, px = idx & 31;
    const float* src = (ic < 64) ? ref : tgt;
    lds[px][ic] = f2h(src[(b * 64 + (ic & 63)) * PLANE + y * HW + x0 + px]);
  }
  __syncthreads();
  for (int idx = threadIdx.x; idx < 512; idx += 256) {
    int px = idx >> 4, g = idx & 15;
    uint4 v = *(const uint4*)&lds[px][g * 8];
    size_t base = ((size_t)(b * HW + y) * HW + x0 + px) * 64;
    if (g < 8)
      *(uint4*)(xref + base + g * 8) = v;
    else
      *(uint4*)(xtgt + base + (g - 8) * 8) = v;
  }
}

__device__ __forceinline__ uint4 blend4(uint4 a, uint4 b, uint4 c, uint4 d,
                                        __half2 h00, __half2 h01, __half2 h10, __half2 h11) {
  union U { uint4 u; __half2 h[4]; };
  U A, B, C, D, R;
  A.u = a; B.u = b; C.u = c; D.u = d;
#pragma unroll
  for (int i = 0; i < 4; ++i)
    R.h[i] = __hfma2(D.h[i], h11, __hfma2(C.h[i], h10, __hfma2(B.h[i], h01, __hmul2(A.h[i], h00))));
  return R.u;
}

// ---------------- megakernel: conv1 -> conv2 -> deform, one 16x16 tile per block ----------------
// 512 thr = 8 waves. LDS: bufA (ref 20x20 halo; hmid 384x64 overlays after conv1),
// bufB (tgt 20x20 halo, reused as deform gather window), offsL (256x20 f32).
// All tiles XOR-swizzled ((rec&7)<<3 short-units) for conflict-free b128 frag reads.
// conv1: hmid on 18x18 (halo for conv2), M padded to 384 px (24 frags, 3/wave).
// hmid store is MASKED to 0 for out-of-image halo pixels (conv2 SAME-pad semantics).
__global__ __launch_bounds__(512, 2) void mega_kernel(
    const unsigned short* __restrict__ xref, const unsigned short* __restrict__ xtgt,
    const unsigned short* __restrict__ w1p, const float* __restrict__ b1,
    const unsigned short* __restrict__ w2p, const float* __restrict__ b2,
    const unsigned short* __restrict__ wdp, float* __restrict__ out) {
  __shared__ __align__(16) unsigned short bufA[400 * 64];  // 51200 B
  __shared__ __align__(16) unsigned short bufB[400 * 64];  // 51200 B
  __shared__ float offsL[256 * 20];                        // 20480 B; total 122880 B

  int b, by, bx;
  tile_from_bid_512(blockIdx.x, b, by, bx);
  const int tid = threadIdx.x, lane = tid & 63, w = tid >> 6;
  const int l15 = lane & 15, lg = lane >> 4;

  const unsigned short* rb = xref + (size_t)b * PLANE * 64;
  const unsigned short* tb = xtgt + (size_t)b * PLANE * 64;

  // ---- stage 20x20 halos (rows by-2..by+17, cols bx-2..bx+17), swizzled ----
  for (int i = tid; i < 3200; i += 512) {
    int rec = i >> 3, g = i & 7;
    int wy = rec / 20, wx = rec - wy * 20;
    int gy = by - 2 + wy, gx = bx - 2 + wx;
    uint4 va = make_uint4(0u, 0u, 0u, 0u), vb = va;
    if ((unsigned)gy < 128u && (unsigned)gx < 128u) {
      size_t o = ((size_t)gy * HW + gx) * 64 + g * 8;
      va = *(const uint4*)(rb + o);
      vb = *(const uint4*)(tb + o);
    }
    int sw = rec * 64 + ((g * 8) ^ ((rec & 7) << 3));
    *(uint4*)(bufA + sw) = va;
    *(uint4*)(bufB + sw) = vb;
  }
  __syncthreads();

  // ---- conv1: hmid[18x18] (p = (hy+1)*18+(hx+1), padded to 384). A=w1(oc), B=pixels ----
  int pyv[3], pxv[3];
#pragma unroll
  for (int n = 0; n < 3; ++n) {
    int p = (w * 3 + n) * 16 + l15;
    p = min(p, 323);
    pyv[n] = p / 18;
    pxv[n] = p - pyv[n] * 18;
  }

  f32x4 acc1[4][3];
#pragma unroll
  for (int mf = 0; mf < 4; ++mf)
#pragma unroll
    for (int n = 0; n < 3; ++n) acc1[mf][n] = (f32x4){0.f, 0.f, 0.f, 0.f};

  for (int c = 0; c < 2; ++c) {
    const unsigned short* src = c ? bufB : bufA;
#pragma unroll
    for (int tap = 0; tap < 9; ++tap) {
      const int ty = tap / 3, tx = tap - ty * 3;
#pragma unroll
      for (int ks = 0; ks < 2; ++ks) {
        f16x8 bp[3];
#pragma unroll
        for (int n = 0; n < 3; ++n) {
          int rec = (pyv[n] + ty) * 20 + pxv[n] + tx;
          bp[n] = *(const f16x8*)(src + rec * 64 + ((ks * 32 + lg * 8) ^ ((rec & 7) << 3)));
        }
        const int kb = tap * 16 + c * 8 + ks * 4 + lg;
        f16x8 aw[4];
#pragma unroll
        for (int mf = 0; mf < 4; ++mf)
          aw[mf] = *(const f16x8*)(w1p + (kb * 64 + mf * 16 + l15) * 8);
#pragma unroll
        for (int mf = 0; mf < 4; ++mf)
#pragma unroll
          for (int n = 0; n < 3; ++n)
            acc1[mf][n] = __builtin_amdgcn_mfma_f32_16x16x32_f16(aw[mf], bp[n], acc1[mf][n], 0, 0, 0);
      }
    }
  }
  __syncthreads();  // all bufA reads done; safe to overlay hmid

  // ---- hmid -> LDS (overlay bufA), MASKED to 0 outside the image ----
  unsigned short* hmidL = bufA;
#pragma unroll
  for (int mf = 0; mf < 4; ++mf) {
    const float4 bv = ((const float4*)b1)[mf * 4 + lg];
#pragma unroll
    for (int n = 0; n < 3; ++n) {
      const int p = (w * 3 + n) * 16 + l15;
      // conv2 SAME-padding: hmid is ZERO outside the image. Halo pixels at
      // global (by-1+py, bx-1+px) beyond [0,128) must store 0, not leaky(b1).
      const bool valid = ((unsigned)(by - 1 + pyv[n]) < 128u) &&
                         ((unsigned)(bx - 1 + pxv[n]) < 128u);
      const float m = valid ? 1.f : 0.f;
      float v0 = acc1[mf][n][0] + bv.x;
      float v1 = acc1[mf][n][1] + bv.y;
      float v2 = acc1[mf][n][2] + bv.z;
      float v3 = acc1[mf][n][3] + bv.w;
      v0 = ((v0 >= 0.f) ? v0 : 0.1f * v0) * m;
      v1 = ((v1 >= 0.f) ? v1 : 0.1f * v1) * m;
      v2 = ((v2 >= 0.f) ? v2 : 0.1f * v2) * m;
      v3 = ((v3 >= 0.f) ? v3 : 0.1f * v3) * m;
      ushort4 s;
      s.x = f2h(v0); s.y = f2h(v1); s.z = f2h(v2); s.w = f2h(v3);
      const int oc = mf * 16 + lg * 4;
      *(ushort4*)(hmidL + p * 64 + (oc ^ ((p & 7) << 3))) = s;
    }
  }
  __syncthreads();

  // ---- conv2 (in LDS): A=hmid pixels, B=w2p (N=32, 18 valid) -> offsL ----
  f32x4 acc2[2][2];
#pragma unroll
  for (int q = 0; q < 2; ++q)
#pragma unroll
    for (int nf = 0; nf < 2; ++nf) acc2[q][nf] = (f32x4){0.f, 0.f, 0.f, 0.f};

#pragma unroll
  for (int tap = 0; tap < 9; ++tap) {
    const int ty = tap / 3, tx = tap - ty * 3;
#pragma unroll
    for (int ks = 0; ks < 2; ++ks) {
      f16x8 ap[2];
#pragma unroll
      for (int q = 0; q < 2; ++q) {
        int p = (w * 2 + q + ty) * 18 + l15 + tx;
        ap[q] = *(const f16x8*)(hmidL + p * 64 + ((ks * 32 + lg * 8) ^ ((p & 7) << 3)));
      }
      const int kb = tap * 8 + ks * 4 + lg;
      f16x8 bw[2];
#pragma unroll
      for (int nf = 0; nf < 2; ++nf)
        bw[nf] = *(const f16x8*)(w2p + (kb * 32 + nf * 16 + l15) * 8);
#pragma unroll
      for (int q = 0; q < 2; ++q)
#pragma unroll
        for (int nf = 0; nf < 2; ++nf)
          acc2[q][nf] = __builtin_amdgcn_mfma_f32_16x16x32_f16(ap[q], bw[nf], acc2[q][nf], 0, 0, 0);
    }
  }
#pragma unroll
  for (int nf = 0; nf < 2; ++nf) {
    const int oc = nf * 16 + l15;
    if (oc < 18) {
      const float bias = b2[oc];
#pragma unroll
      for (int q = 0; q < 2; ++q)
#pragma unroll
        for (int reg = 0; reg < 4; ++reg) {
          int px = (w * 2 + q) * 16 + lg * 4 + reg;
          offsL[px * 20 + oc] = acc2[q][nf][reg] + bias;
        }
    }
  }
  __syncthreads();

  // ---- deform: gather from bufB window + fp16 MFMA. A=sampled px, B=wd ----
  f32x4 acc[2][4];
#pragma unroll
  for (int q = 0; q < 2; ++q)
#pragma unroll
    for (int nf = 0; nf < 4; ++nf) acc[q][nf] = (f32x4){0.f, 0.f, 0.f, 0.f};

  const int x = bx + l15;

  for (int kk = 0; kk < 9; ++kk) {
    const int kdy = kk / 3 - 1, kdx = kk - (kk / 3) * 3 - 1;
    f16x8 af[2][2];
#pragma unroll
    for (int q = 0; q < 2; ++q) {
      const int y = by + w * 2 + q;
      const int px_lin = (w * 2 + q) * 16 + l15;
      float dy = offsL[px_lin * 20 + kk * 2];
      float dx = offsL[px_lin * 20 + kk * 2 + 1];
      float ys = (float)(y + kdy) + dy;
      float xs = (float)(x + kdx) + dx;
      float y0f = floorf(ys), x0f = floorf(xs);
      float wy = ys - y0f, wx = xs - x0f;
      int y0 = (int)y0f, x0i = (int)x0f;
      int y1 = y0 + 1, x1 = x0i + 1;
      float vy0 = (y0 >= 0 && y0 < HW) ? 1.f : 0.f;
      float vy1 = (y1 >= 0 && y1 < HW) ? 1.f : 0.f;
      float vx0 = (x0i >= 0 && x0i < HW) ? 1.f : 0.f;
      float vx1 = (x1 >= 0 && x1 < HW) ? 1.f : 0.f;
      int y0c = min(max(y0, 0), HW - 1), y1c = min(max(y1, 0), HW - 1);
      int x0c = min(max(x0i, 0), HW - 1), x1c = min(max(x1, 0), HW - 1);
      __half2 h00 = __float2half2_rn((1.f - wy) * (1.f - wx) * vy0 * vx0);
      __half2 h01 = __float2half2_rn((1.f - wy) * wx * vy0 * vx1);
      __half2 h10 = __float2half2_rn(wy * (1.f - wx) * vy1 * vx0);
      __half2 h11 = __float2half2_rn(wy * wx * vy1 * vx1);

      const int wy0 = y0c - by + 2, wy1 = y1c - by + 2;
      const int wx0 = x0c - bx + 2, wx1 = x1c - bx + 2;
      const bool inw = ((unsigned)wy0 < 20u) && ((unsigned)wy1 < 20u) &&
                       ((unsigned)wx0 < 20u) && ((unsigned)wx1 < 20u);
      uint4 c00[2], c01[2], c10[2], c11[2];
      if (inw) {
        const int r00 = wy0 * 20 + wx0, r01 = wy0 * 20 + wx1;
        const int r10 = wy1 * 20 + wx0, r11 = wy1 * 20 + wx1;
#pragma unroll
        for (int ks = 0; ks < 2; ++ks) {
          const int ko = (ks * 32 + lg * 8);
          c00[ks] = *(const uint4*)(bufB + r00 * 64 + (ko ^ ((r00 & 7) << 3)));
          c01[ks] = *(const uint4*)(bufB + r01 * 64 + (ko ^ ((r01 & 7) << 3)));
          c10[ks] = *(const uint4*)(bufB + r10 * 64 + (ko ^ ((r10 & 7) << 3)));
          c11[ks] = *(const uint4*)(bufB + r11 * 64 + (ko ^ ((r11 & 7) << 3)));
        }
      } else {
        const unsigned short* p00 = tb + (y0c * HW + x0c) * 64 + lg * 8;
        const unsigned short* p01 = tb + (y0c * HW + x1c) * 64 + lg * 8;
        const unsigned short* p10 = tb + (y1c * HW + x0c) * 64 + lg * 8;
        const unsigned short* p11 = tb + (y1c * HW + x1c) * 64 + lg * 8;
#pragma unroll
        for (int ks = 0; ks < 2; ++ks) {
          c00[ks] = *(const uint4*)(p00 + ks * 32);
          c01[ks] = *(const uint4*)(p01 + ks * 32);
          c10[ks] = *(const uint4*)(p10 + ks * 32);
          c11[ks] = *(const uint4*)(p11 + ks * 32);
        }
      }
#pragma unroll
      for (int ks = 0; ks < 2; ++ks) {
        uint4 r = blend4(c00[ks], c01[ks], c10[ks], c11[ks], h00, h01, h10, h11);
        af[q][ks] = *(const f16x8*)&r;
      }
    }

#pragma unroll
    for (int ks = 0; ks < 2; ++ks) {
      const int kb = kk * 8 + ks * 4 + lg;
      f16x8 bw[4];
#pragma unroll
      for (int nf = 0; nf < 4; ++nf)
        bw[nf] = *(const f16x8*)(wdp + (kb * 64 + nf * 16 + l15) * 8);
#pragma unroll
      for (int q = 0; q < 2; ++q)
#pragma unroll
        for (int nf = 0; nf < 4; ++nf)
          acc[q][nf] = __builtin_amdgcn_mfma_f32_16x16x32_f16(af[q][ks], bw[nf], acc[q][nf], 0, 0, 0);
    }
  }

  const int px0 = bx + lg * 4;
#pragma unroll
  for (int q = 0; q < 2; ++q) {
    const int py = by + w * 2 + q;
#pragma unroll
    for (int nf = 0; nf < 4; ++nf) {
      const int oc = nf * 16 + l15;
      float4 o;
      o.x = acc[q][nf][0];
      o.y = acc[q][nf][1];
      o.z = acc[q][nf][2];
      o.w = acc[q][nf][3];
      *(float4*)(out + (size_t)(b * 64 + oc) * PLANE + py * HW + px0) = o;
    }
  }
}

extern "C" void kernel_launch(void* const* d_in, const int* in_sizes, int n_in,
                              void* d_out, int out_size, void* d_ws, size_t ws_size,
                              hipStream_t stream) {
  const float* ref = (const float*)d_in[0];
  const float* tgt = (const float*)d_in[1];
  const float* w1  = (const float*)d_in[2];
  const float* b1  = (const float*)d_in[3];
  const float* w2  = (const float*)d_in[4];
  const float* b2  = (const float*)d_in[5];
  const float* wd  = (const float*)d_in[6];
  float* out = (float*)d_out;

  char* ws = (char*)d_ws;
  unsigned short* xref = (unsigned short*)ws;                   // 16777216 B
  unsigned short* xtgt = (unsigned short*)(ws + 16777216);      // 16777216 B
  unsigned short* w1p  = (unsigned short*)(ws + 33554432);      // 147456 B
  unsigned short* w2p  = (unsigned short*)(ws + 33701888);      // 36864 B
  unsigned short* wdp  = (unsigned short*)(ws + 33738752);      // 73728 B; end = 33812480

  pack_all_kernel<<<504, 256, 0, stream>>>(w1, w2, wd, w1p, w2p, wdp);

  to_nhwc_kernel<<<dim3(4, 128, 8), 256, 0, stream>>>(ref, tgt, xref, xtgt);

  mega_kernel<<<512, 512, 0, stream>>>(xref, xtgt, w1p, b1, w2p, b2, wdp, out);
}

// Round 10
// 91.064 us; speedup vs baseline: 1.1602x; 1.1602x over previous
//
#include <hip/hip_runtime.h>
#include <hip/hip_fp16.h>

#define HW 128
#define PLANE (HW * HW)
#define WSTR 72   // shorts per window record (20x20 halo), 144 B row -> bank stride 4
#define OSTR 22   // floats per offsL pixel row

typedef __attribute__((ext_vector_type(8))) _Float16 f16x8;
typedef __attribute__((ext_vector_type(4))) float f32x4;

__device__ __forceinline__ unsigned short f2h(float f) {
  return __half_as_ushort(__float2half(f));
}

// XCD-aware bijective swizzle (nwg % 8 == 0): XCD k gets a contiguous chunk.
__device__ __forceinline__ void tile_from_bid_512(int bid, int& b, int& by, int& bx) {
  int wg = (bid & 7) * 64 + (bid >> 3);
  b = wg >> 6;
  int t = wg & 63;
  by = (t >> 3) << 4;
  bx = (t & 7) << 4;
}

// ---------------- fused weight packing (all three) ----------------
__global__ __launch_bounds__(256) void pack_all_kernel(
    const float* __restrict__ w1, const float* __restrict__ w2,
    const float* __restrict__ wd, unsigned short* __restrict__ w1p,
    unsigned short* __restrict__ w2p, unsigned short* __restrict__ wdp) {
  int idx = blockIdx.x * 256 + threadIdx.x;
  if (idx < 73728) {
    int k = idx >> 6, n = idx & 63;
    int tap = k >> 7, ic = k & 127;
    w1p[((k >> 3) * 64 + n) * 8 + (k & 7)] = f2h(w1[(n * 128 + ic) * 9 + tap]);
  } else if (idx < 73728 + 18432) {
    int i = idx - 73728;
    int k = i >> 5, n = i & 31;
    int tap = k >> 6, ic = k & 63;
    float v = (n < 18) ? w2[(n * 64 + ic) * 9 + tap] : 0.f;
    w2p[((k >> 3) * 32 + n) * 8 + (k & 7)] = f2h(v);
  } else if (idx < 73728 + 18432 + 36864) {
    int i = idx - 73728 - 18432;
    int k = i >> 6, n = i & 63;
    int tap = k >> 6, ic = k & 63;
    wdp[((k >> 3) * 64 + n) * 8 + (k & 7)] = f2h(wd[(n * 64 + ic) * 9 + tap]);
  }
}

// ---------------- ref,tgt NCHW fp32 -> NHWC fp16 ----------------
__global__ __launch_bounds__(256) void to_nhwc_kernel(
    const float* __restrict__ ref, const float* __restrict__ tgt,
    unsigned short* __restrict__ xref, unsigned short* __restrict__ xtgt) {
  __shared__ unsigned short lds[32][136];
  const int b = blockIdx.z, y = blockIdx.y, x0 = blockIdx.x * 32;
  for (int idx = threadIdx.x; idx < 4096; idx += 256) {
    int ic = idx >> 5, px = idx & 31;
    const float* src = (ic < 64) ? ref : tgt;
    lds[px][ic] = f2h(src[(b * 64 + (ic & 63)) * PLANE + y * HW + x0 + px]);
  }
  __syncthreads();
  for (int idx = threadIdx.x; idx < 512; idx += 256) {
    int px = idx >> 4, g = idx & 15;
    uint4 v = *(const uint4*)&lds[px][g * 8];
    size_t base = ((size_t)(b * HW + y) * HW + x0 + px) * 64;
    if (g < 8)
      *(uint4*)(xref + base + g * 8) = v;
    else
      *(uint4*)(xtgt + base + (g - 8) * 8) = v;
  }
}

__device__ __forceinline__ uint4 blend4(uint4 a, uint4 b, uint4 c, uint4 d,
                                        __half2 h00, __half2 h01, __half2 h10, __half2 h11) {
  union U { uint4 u; __half2 h[4]; };
  U A, B, C, D, R;
  A.u = a; B.u = b; C.u = c; D.u = d;
#pragma unroll
  for (int i = 0; i < 4; ++i)
    R.h[i] = __hfma2(D.h[i], h11, __hfma2(C.h[i], h10, __hfma2(B.h[i], h01, __hmul2(A.h[i], h00))));
  return R.u;
}

// ---------------- megakernel v2: one time-multiplexed window buffer ----------------
// 512 thr = 8 waves; LDS = bufW (20x20 halo, stride-72 pad, conflict-free) + offsL.
// 80128 B total -> 2 blocks/CU (16 waves/CU): resident blocks overlap phases.
// Sequence: stage tgt -> conv1(tgt) -> stage ref -> conv1(ref) -> hmid overlay
//           -> conv2 -> re-stage tgt -> deform.  (7 barriers)
__global__ __launch_bounds__(512, 4) void mega_kernel(
    const unsigned short* __restrict__ xref, const unsigned short* __restrict__ xtgt,
    const unsigned short* __restrict__ w1p, const float* __restrict__ b1,
    const unsigned short* __restrict__ w2p, const float* __restrict__ b2,
    const unsigned short* __restrict__ wdp, float* __restrict__ out) {
  __shared__ __align__(16) unsigned short bufW[400 * WSTR];  // 57600 B
  __shared__ __align__(8) float offsL[256 * OSTR];           // 22528 B; total 80128 B

  int b, by, bx;
  tile_from_bid_512(blockIdx.x, b, by, bx);
  const int tid = threadIdx.x, lane = tid & 63, w = tid >> 6;
  const int l15 = lane & 15, lg = lane >> 4;

  const unsigned short* rb = xref + (size_t)b * PLANE * 64;
  const unsigned short* tb = xtgt + (size_t)b * PLANE * 64;

  // stage a 20x20 halo (rows by-2..by+17, cols bx-2..bx+17) into bufW
  auto STAGE = [&](const unsigned short* src) {
    for (int i = tid; i < 3200; i += 512) {
      int rec = i >> 3, g = i & 7;
      int wy = rec / 20, wx = rec - wy * 20;
      int gy = by - 2 + wy, gx = bx - 2 + wx;
      uint4 v = make_uint4(0u, 0u, 0u, 0u);
      if ((unsigned)gy < 128u && (unsigned)gx < 128u)
        v = *(const uint4*)(src + ((size_t)gy * HW + gx) * 64 + g * 8);
      *(uint4*)(bufW + rec * WSTR + g * 8) = v;
    }
  };

  // conv1 pixel assignment: 384 padded px (24 frags, 3/wave), clamped to 323
  int pyv[3], pxv[3];
#pragma unroll
  for (int n = 0; n < 3; ++n) {
    int p = (w * 3 + n) * 16 + l15;
    p = min(p, 323);
    pyv[n] = p / 18;
    pxv[n] = p - pyv[n] * 18;
  }

  f32x4 acc1[4][3];
#pragma unroll
  for (int mf = 0; mf < 4; ++mf)
#pragma unroll
    for (int n = 0; n < 3; ++n) acc1[mf][n] = (f32x4){0.f, 0.f, 0.f, 0.f};

  // one K-half (c=0 ref, c=1 tgt) of conv1 over whatever is staged in bufW
  auto CONV1_HALF = [&](int c) {
#pragma unroll
    for (int tap = 0; tap < 9; ++tap) {
      const int ty = tap / 3, tx = tap - ty * 3;
#pragma unroll
      for (int ks = 0; ks < 2; ++ks) {
        f16x8 bp[3];
#pragma unroll
        for (int n = 0; n < 3; ++n) {
          int rec = (pyv[n] + ty) * 20 + pxv[n] + tx;
          bp[n] = *(const f16x8*)(bufW + rec * WSTR + ks * 32 + lg * 8);
        }
        const int kb = tap * 16 + c * 8 + ks * 4 + lg;
        f16x8 aw[4];
#pragma unroll
        for (int mf = 0; mf < 4; ++mf)
          aw[mf] = *(const f16x8*)(w1p + (kb * 64 + mf * 16 + l15) * 8);
#pragma unroll
        for (int mf = 0; mf < 4; ++mf)
#pragma unroll
          for (int n = 0; n < 3; ++n)
            acc1[mf][n] = __builtin_amdgcn_mfma_f32_16x16x32_f16(aw[mf], bp[n], acc1[mf][n], 0, 0, 0);
      }
    }
  };

  STAGE(tb);            // s1: tgt window
  __syncthreads();
  CONV1_HALF(1);        // s2: tgt half of K
  __syncthreads();
  STAGE(rb);            // s3: ref window (overwrite)
  __syncthreads();
  CONV1_HALF(0);        // s4: ref half of K
  __syncthreads();

  // s5: hmid -> bufW overlay (18x18, stride WSTR), MASKED to 0 outside image
  unsigned short* hmidL = bufW;
#pragma unroll
  for (int mf = 0; mf < 4; ++mf) {
    const float4 bv = ((const float4*)b1)[mf * 4 + lg];
#pragma unroll
    for (int n = 0; n < 3; ++n) {
      const int p = (w * 3 + n) * 16 + l15;
      const bool valid = ((unsigned)(by - 1 + pyv[n]) < 128u) &&
                         ((unsigned)(bx - 1 + pxv[n]) < 128u);
      const float m = valid ? 1.f : 0.f;
      float v0 = acc1[mf][n][0] + bv.x;
      float v1 = acc1[mf][n][1] + bv.y;
      float v2 = acc1[mf][n][2] + bv.z;
      float v3 = acc1[mf][n][3] + bv.w;
      v0 = ((v0 >= 0.f) ? v0 : 0.1f * v0) * m;
      v1 = ((v1 >= 0.f) ? v1 : 0.1f * v1) * m;
      v2 = ((v2 >= 0.f) ? v2 : 0.1f * v2) * m;
      v3 = ((v3 >= 0.f) ? v3 : 0.1f * v3) * m;
      ushort4 s;
      s.x = f2h(v0); s.y = f2h(v1); s.z = f2h(v2); s.w = f2h(v3);
      *(ushort4*)(hmidL + p * WSTR + mf * 16 + lg * 4) = s;
    }
  }
  __syncthreads();

  // s6: conv2 (in LDS): A=hmid pixels, B=w2p (N=32, 18 valid) -> offsL
  f32x4 acc2[2][2];
#pragma unroll
  for (int q = 0; q < 2; ++q)
#pragma unroll
    for (int nf = 0; nf < 2; ++nf) acc2[q][nf] = (f32x4){0.f, 0.f, 0.f, 0.f};

#pragma unroll
  for (int tap = 0; tap < 9; ++tap) {
    const int ty = tap / 3, tx = tap - ty * 3;
#pragma unroll
    for (int ks = 0; ks < 2; ++ks) {
      f16x8 ap[2];
#pragma unroll
      for (int q = 0; q < 2; ++q) {
        int p = (w * 2 + q + ty) * 18 + l15 + tx;
        ap[q] = *(const f16x8*)(hmidL + p * WSTR + ks * 32 + lg * 8);
      }
      const int kb = tap * 8 + ks * 4 + lg;
      f16x8 bw[2];
#pragma unroll
      for (int nf = 0; nf < 2; ++nf)
        bw[nf] = *(const f16x8*)(w2p + (kb * 32 + nf * 16 + l15) * 8);
#pragma unroll
      for (int q = 0; q < 2; ++q)
#pragma unroll
        for (int nf = 0; nf < 2; ++nf)
          acc2[q][nf] = __builtin_amdgcn_mfma_f32_16x16x32_f16(ap[q], bw[nf], acc2[q][nf], 0, 0, 0);
    }
  }
#pragma unroll
  for (int nf = 0; nf < 2; ++nf) {
    const int oc = nf * 16 + l15;
    if (oc < 18) {
      const float bias = b2[oc];
#pragma unroll
      for (int q = 0; q < 2; ++q)
#pragma unroll
        for (int reg = 0; reg < 4; ++reg) {
          int px = (w * 2 + q) * 16 + lg * 4 + reg;
          offsL[px * OSTR + oc] = acc2[q][nf][reg] + bias;
        }
    }
  }
  __syncthreads();

  STAGE(tb);            // s7: re-stage tgt window (bufW dead after conv2)
  __syncthreads();

  // s8: deform: gather from bufW + fp16 MFMA. A=sampled px, B=wd
  f32x4 acc[2][4];
#pragma unroll
  for (int q = 0; q < 2; ++q)
#pragma unroll
    for (int nf = 0; nf < 4; ++nf) acc[q][nf] = (f32x4){0.f, 0.f, 0.f, 0.f};

  const int x = bx + l15;

  for (int kk = 0; kk < 9; ++kk) {
    const int kdy = kk / 3 - 1, kdx = kk - (kk / 3) * 3 - 1;
    f16x8 af[2][2];
#pragma unroll
    for (int q = 0; q < 2; ++q) {
      const int y = by + w * 2 + q;
      const int px_lin = (w * 2 + q) * 16 + l15;
      const float2 o2 = *(const float2*)(&offsL[px_lin * OSTR + kk * 2]);
      float ys = (float)(y + kdy) + o2.x;
      float xs = (float)(x + kdx) + o2.y;
      float y0f = floorf(ys), x0f = floorf(xs);
      float wy = ys - y0f, wx = xs - x0f;
      int y0 = (int)y0f, x0i = (int)x0f;
      int y1 = y0 + 1, x1 = x0i + 1;
      float vy0 = (y0 >= 0 && y0 < HW) ? 1.f : 0.f;
      float vy1 = (y1 >= 0 && y1 < HW) ? 1.f : 0.f;
      float vx0 = (x0i >= 0 && x0i < HW) ? 1.f : 0.f;
      float vx1 = (x1 >= 0 && x1 < HW) ? 1.f : 0.f;
      int y0c = min(max(y0, 0), HW - 1), y1c = min(max(y1, 0), HW - 1);
      int x0c = min(max(x0i, 0), HW - 1), x1c = min(max(x1, 0), HW - 1);
      __half2 h00 = __float2half2_rn((1.f - wy) * (1.f - wx) * vy0 * vx0);
      __half2 h01 = __float2half2_rn((1.f - wy) * wx * vy0 * vx1);
      __half2 h10 = __float2half2_rn(wy * (1.f - wx) * vy1 * vx0);
      __half2 h11 = __float2half2_rn(wy * wx * vy1 * vx1);

      const int wy0 = y0c - by + 2, wy1 = y1c - by + 2;
      const int wx0 = x0c - bx + 2, wx1 = x1c - bx + 2;
      const bool inw = ((unsigned)wy0 < 20u) && ((unsigned)wy1 < 20u) &&
                       ((unsigned)wx0 < 20u) && ((unsigned)wx1 < 20u);
      uint4 c00[2], c01[2], c10[2], c11[2];
      if (inw) {
        const int r00 = wy0 * 20 + wx0, r01 = wy0 * 20 + wx1;
        const int r10 = wy1 * 20 + wx0, r11 = wy1 * 20 + wx1;
#pragma unroll
        for (int ks = 0; ks < 2; ++ks) {
          const int ko = ks * 32 + lg * 8;
          c00[ks] = *(const uint4*)(bufW + r00 * WSTR + ko);
          c01[ks] = *(const uint4*)(bufW + r01 * WSTR + ko);
          c10[ks] = *(const uint4*)(bufW + r10 * WSTR + ko);
          c11[ks] = *(const uint4*)(bufW + r11 * WSTR + ko);
        }
      } else {
        const unsigned short* p00 = tb + (y0c * HW + x0c) * 64 + lg * 8;
        const unsigned short* p01 = tb + (y0c * HW + x1c) * 64 + lg * 8;
        const unsigned short* p10 = tb + (y1c * HW + x0c) * 64 + lg * 8;
        const unsigned short* p11 = tb + (y1c * HW + x1c) * 64 + lg * 8;
#pragma unroll
        for (int ks = 0; ks < 2; ++ks) {
          c00[ks] = *(const uint4*)(p00 + ks * 32);
          c01[ks] = *(const uint4*)(p01 + ks * 32);
          c10[ks] = *(const uint4*)(p10 + ks * 32);
          c11[ks] = *(const uint4*)(p11 + ks * 32);
        }
      }
#pragma unroll
      for (int ks = 0; ks < 2; ++ks) {
        uint4 r = blend4(c00[ks], c01[ks], c10[ks], c11[ks], h00, h01, h10, h11);
        af[q][ks] = *(const f16x8*)&r;
      }
    }

#pragma unroll
    for (int ks = 0; ks < 2; ++ks) {
      const int kb = kk * 8 + ks * 4 + lg;
      f16x8 bw[4];
#pragma unroll
      for (int nf = 0; nf < 4; ++nf)
        bw[nf] = *(const f16x8*)(wdp + (kb * 64 + nf * 16 + l15) * 8);
#pragma unroll
      for (int q = 0; q < 2; ++q)
#pragma unroll
        for (int nf = 0; nf < 4; ++nf)
          acc[q][nf] = __builtin_amdgcn_mfma_f32_16x16x32_f16(af[q][ks], bw[nf], acc[q][nf], 0, 0, 0);
    }
  }

  const int px0 = bx + lg * 4;
#pragma unroll
  for (int q = 0; q < 2; ++q) {
    const int py = by + w * 2 + q;
#pragma unroll
    for (int nf = 0; nf < 4; ++nf) {
      const int oc = nf * 16 + l15;
      float4 o;
      o.x = acc[q][nf][0];
      o.y = acc[q][nf][1];
      o.z = acc[q][nf][2];
      o.w = acc[q][nf][3];
      *(float4*)(out + (size_t)(b * 64 + oc) * PLANE + py * HW + px0) = o;
    }
  }
}

extern "C" void kernel_launch(void* const* d_in, const int* in_sizes, int n_in,
                              void* d_out, int out_size, void* d_ws, size_t ws_size,
                              hipStream_t stream) {
  const float* ref = (const float*)d_in[0];
  const float* tgt = (const float*)d_in[1];
  const float* w1  = (const float*)d_in[2];
  const float* b1  = (const float*)d_in[3];
  const float* w2  = (const float*)d_in[4];
  const float* b2  = (const float*)d_in[5];
  const float* wd  = (const float*)d_in[6];
  float* out = (float*)d_out;

  char* ws = (char*)d_ws;
  unsigned short* xref = (unsigned short*)ws;                   // 16777216 B
  unsigned short* xtgt = (unsigned short*)(ws + 16777216);      // 16777216 B
  unsigned short* w1p  = (unsigned short*)(ws + 33554432);      // 147456 B
  unsigned short* w2p  = (unsigned short*)(ws + 33701888);      // 36864 B
  unsigned short* wdp  = (unsigned short*)(ws + 33738752);      // 73728 B; end = 33812480

  pack_all_kernel<<<504, 256, 0, stream>>>(w1, w2, wd, w1p, w2p, wdp);

  to_nhwc_kernel<<<dim3(4, 128, 8), 256, 0, stream>>>(ref, tgt, xref, xtgt);

  mega_kernel<<<512, 512, 0, stream>>>(xref, xtgt, w1p, b1, w2p, b2, wdp, out);
}